// Round 5
// baseline (959.424 us; speedup 1.0000x reference)
//
#include <hip/hip_runtime.h>

// BlkQ4Linear: out[m,n] = sum_k in[m,k]*(q[n,k]-zp[n,k/64])*s[n,k/64] + bias[n]
// M=4096 K=4096 N=11008.
// Round 8: software-pipeline the 8-phase GEMM. R7 post-mortem: phase time
// 1131 cyc = ~590 cyc LDS read service SERIAL with 620 cyc MFMA (reads
// issued, barrier, lgkmcnt(0), MFMA). Fix: reads for phase p+1 issue in
// phase p before MFMA(p); counted lgkmcnt(N) in p+1 drains only the older
// set -> LDS service overlaps the matrix pipe. One barrier per phase.
// Ledger (re-derived, FIFO-simulated, cyclically consistent):
//   stages/iter unchanged: P1:A(t+1,h1)b1 P2:B(t+1,h1)b1 P3:A(t+2,h0)b0
//   P4:B(t+2,h0)b0 P5:A(t+2,h1)b0 P6:B(t+2,h1)b0 P7:A(t+3,h0)b1 P8:B(t+3,h0)b1
//   reads(issued in-phase, consumed next phase):
//   P1:bf1<-b0h1 P2:afb<-b0h1 P3:- P4:afa,bf0<-b1h0 P5:bf1<-b1h1
//   P6:afb<-b1h1 P7:- P8:afa,bf0<-b0h0(t+2)
//   vmcnt guards BEFORE the phase-end barrier (guard->barrier publishes all
//   waves' DMAs): endP3:6 endP4:4 endP7:6 endP8:4. Outstanding cycle:
//   4 ->P1 6 ->P2 8 ->P3 10-g6 ->P4 8-g4 ->P5 6 ->P6 8 ->P7 10-g6 ->P8 8-g4 -> 4. OK
//   lgkm before MFMA = #reads just issued: P1:4 P2:8 P3:0 P4:- P5:4 P6:8 P7:0 P8:-
//   WAR (read-issue overwriting frag regs): always >=1 barrier after last
//   MFMA consumer (same pattern R7 exercised). Read sources vs next-phase
//   stage regions: all disjoint (enumerated per phase).

#define BM 128
#define BN 128
#define BK 64
#define LDSN 72  // fused-fallback LDS pad

typedef __attribute__((ext_vector_type(8))) short bf16x8;
typedef __attribute__((ext_vector_type(4))) float f32x4;

__device__ __forceinline__ unsigned short f2bf(float f) {
    union { float f; unsigned int u; } v; v.f = f;
    unsigned int u = v.u;
    u += 0x7FFFu + ((u >> 16) & 1u);   // RNE
    return (unsigned short)(u >> 16);
}
__device__ __forceinline__ unsigned int pack2(float a, float b) {
    return (unsigned int)f2bf(a) | ((unsigned int)f2bf(b) << 16);
}

__device__ __forceinline__ void gl_lds16(const void* gp, void* lp) {
    __builtin_amdgcn_global_load_lds(
        (const __attribute__((address_space(1))) unsigned int*)gp,
        (__attribute__((address_space(3))) unsigned int*)lp,
        16, 0, 0);
}

__device__ __forceinline__ unsigned lds_off(const void* p) {
    return (unsigned)(unsigned long long)
        (const __attribute__((address_space(3))) void*)p;
}

template<int IMM>
__device__ __forceinline__ bf16x8 ds128(unsigned a) {
    bf16x8 d;
    asm volatile("ds_read_b128 %0, %1 offset:%2"
                 : "=v"(d) : "v"(a), "i"(IMM));
    return d;
}

// ---------------- Pass 1 (merged): A fp32->bf16 AND Q int32->bf16 W ----------
__global__ __launch_bounds__(256)
void prep_kernel(const float* __restrict__ A, const int* __restrict__ Q,
                 const float* __restrict__ S, const int* __restrict__ Zp,
                 unsigned short* __restrict__ Ab, unsigned short* __restrict__ W,
                 int M, int K, int nb)
{
    const int y = blockIdx.y;
    const int k = (blockIdx.x * 256 + threadIdx.x) * 8;
    if (k >= K) return;
    if (y < M) {
        const float4* ap = (const float4*)(A + (size_t)y * K + k);
        float4 a0 = ap[0], a1 = ap[1];
        uint4 o;
        o.x = pack2(a0.x, a0.y); o.y = pack2(a0.z, a0.w);
        o.z = pack2(a1.x, a1.y); o.w = pack2(a1.z, a1.w);
        *(uint4*)(Ab + (size_t)y * K + k) = o;
    } else {
        const int n = y - M;
        const int kb = k >> 6;
        const float s  = S[(size_t)n * nb + kb];
        const float zs = (float)Zp[(size_t)n * nb + kb] * s;
        const int4* qp = (const int4*)(Q + (size_t)n * K + k);
        int4 q0 = qp[0], q1 = qp[1];
        uint4 o;
        o.x = pack2((float)q0.x * s - zs, (float)q0.y * s - zs);
        o.y = pack2((float)q0.z * s - zs, (float)q0.w * s - zs);
        o.z = pack2((float)q1.x * s - zs, (float)q1.y * s - zs);
        o.w = pack2((float)q1.z * s - zs, (float)q1.w * s - zs);
        *(uint4*)(W + (size_t)n * K + k) = o;
    }
}

// ---------------- Pass 2: 256x256 8-phase pipelined bf16 GEMM ---------------

#define G8_BARRIER() asm volatile("s_barrier" ::: "memory")
#define G8_VMCNT(n)  asm volatile("s_waitcnt vmcnt(" #n ")" ::: "memory")
#define G8_LGKMC(n)  do { asm volatile("s_waitcnt lgkmcnt(" #n ")" ::: "memory"); \
    __builtin_amdgcn_sched_barrier(0); } while (0)

#define G8_STAGE(G, kt, h, base, b)                                          \
  do {                                                                       \
    const unsigned short* _s = (G) + (long)(kt) * 64 + (long)(h) * 128 * K;  \
    gl_lds16(_s + aoff0, (base) + (b) * 32768 + (h) * 16384 + lds0);         \
    gl_lds16(_s + aoff1, (base) + (b) * 32768 + (h) * 16384 + lds1);         \
  } while (0)

#define G8_LOAD_AF(b, mh, AF)                                                \
  AF[0][0] = ds128<(b)*32768 + (mh)*16384 + 0*2048>(pA0);                    \
  AF[1][0] = ds128<(b)*32768 + (mh)*16384 + 1*2048>(pA0);                    \
  AF[2][0] = ds128<(b)*32768 + (mh)*16384 + 2*2048>(pA0);                    \
  AF[3][0] = ds128<(b)*32768 + (mh)*16384 + 3*2048>(pA0);                    \
  AF[0][1] = ds128<(b)*32768 + (mh)*16384 + 0*2048>(pA1);                    \
  AF[1][1] = ds128<(b)*32768 + (mh)*16384 + 1*2048>(pA1);                    \
  AF[2][1] = ds128<(b)*32768 + (mh)*16384 + 2*2048>(pA1);                    \
  AF[3][1] = ds128<(b)*32768 + (mh)*16384 + 3*2048>(pA1);

#define G8_LOAD_BF(b, nh, BF)                                                \
  BF[0][0] = ds128<(b)*32768 + (nh)*16384 + 0*2048>(pB0);                    \
  BF[1][0] = ds128<(b)*32768 + (nh)*16384 + 1*2048>(pB0);                    \
  BF[0][1] = ds128<(b)*32768 + (nh)*16384 + 0*2048>(pB1);                    \
  BF[1][1] = ds128<(b)*32768 + (nh)*16384 + 1*2048>(pB1);

#define G8_MFMA(q, AF, BF)                                                   \
  __builtin_amdgcn_s_setprio(1);                                             \
  { _Pragma("unroll") for (int _i = 0; _i < 4; ++_i)                         \
    _Pragma("unroll") for (int _j = 0; _j < 2; ++_j) {                       \
      acc[q][_i][_j] = __builtin_amdgcn_mfma_f32_16x16x32_bf16(              \
          AF[_i][0], BF[_j][0], acc[q][_i][_j], 0, 0, 0);                    \
      acc[q][_i][_j] = __builtin_amdgcn_mfma_f32_16x16x32_bf16(              \
          AF[_i][1], BF[_j][1], acc[q][_i][_j], 0, 0, 0);                    \
  } }                                                                        \
  __builtin_amdgcn_s_setprio(0);

__global__ __launch_bounds__(512, 2)
void gemm8_kernel(const unsigned short* __restrict__ Ab,
                  const unsigned short* __restrict__ Wb,
                  const float* __restrict__ bias, float* __restrict__ C,
                  int M, int N, int K)
{
    __shared__ __align__(16) unsigned short As[2][256][64];
    __shared__ __align__(16) unsigned short Bs[2][256][64];

    const int tid  = threadIdx.x;

    // Bijective XCD-chunked swizzle (T1/m204), M-fastest decode.
    const int nwg = gridDim.x;
    int wg = blockIdx.x;
    {
        const int q8 = nwg >> 3, r8 = nwg & 7, x = wg & 7, s = wg >> 3;
        wg = (x < r8 ? x * (q8 + 1) : r8 * (q8 + 1) + (x - r8) * q8) + s;
    }
    const int gx = M / 256;
    const int m0 = (wg % gx) * 256;
    const int n0 = (wg / gx) * 256;

    const int lane = tid & 63;
    const int wave = tid >> 6;
    const int ww   = wave >> 2;       // 0..1, m-dir
    const int wv   = wave & 3;        // 0..3, n-dir
    const int fr   = lane & 15;
    const int quad = lane >> 4;
    const int sw   = fr & 7;

    // staging constants: thread covers chunks tid and 512+tid of each half
    const int rl0 = tid >> 3;
    const int rl1 = (512 + tid) >> 3;
    const int pp  = tid & 7;
    const long aoff0 = (long)rl0 * K + (long)((pp ^ (rl0 & 7)) * 8);
    const long aoff1 = (long)rl1 * K + (long)((pp ^ (rl1 & 7)) * 8);
    const int lds0 = tid * 16;
    const int lds1 = (512 + tid) * 16;

    // fragment-read bases: logical chunk l=ks*4+quad at physical (l^sw)*16
    const int ck0 = ((quad    ) ^ sw) * 16;
    const int ck1 = ((quad + 4) ^ sw) * 16;
    const int arow = ww * 64 + fr;
    const int brow = wv * 32 + fr;

    char* AsB = (char*)&As[0][0][0];
    char* BsB = (char*)&Bs[0][0][0];
    const unsigned pA0 = lds_off(AsB) + arow * 128 + ck0;
    const unsigned pA1 = lds_off(AsB) + arow * 128 + ck1;
    const unsigned pB0 = lds_off(BsB) + brow * 128 + ck0;
    const unsigned pB1 = lds_off(BsB) + brow * 128 + ck1;

    const unsigned short* Ag = Ab + (size_t)m0 * K;
    const unsigned short* Bg = Wb + (size_t)n0 * K;

    f32x4 acc[4][4][2];
    #pragma unroll
    for (int q = 0; q < 4; ++q)
        #pragma unroll
        for (int i = 0; i < 4; ++i)
            #pragma unroll
            for (int j = 0; j < 2; ++j)
                acc[q][i][j] = (f32x4){0.f, 0.f, 0.f, 0.f};

    bf16x8 afa[4][2], afb[4][2], bf0[2][2], bf1[2][2];

    // ---- prologue: tile0 (buf0) + A/B(1,h0) (buf1); then first reads ----
    G8_STAGE(Ag, 0, 0, AsB, 0);
    G8_STAGE(Bg, 0, 0, BsB, 0);
    G8_STAGE(Ag, 0, 1, AsB, 0);
    G8_STAGE(Bg, 0, 1, BsB, 0);
    G8_STAGE(Ag, 1, 0, AsB, 1);
    G8_STAGE(Bg, 1, 0, BsB, 1);
    G8_VMCNT(4);              // tile0 landed; {A,B}(1,h0) in flight
    G8_BARRIER();
    G8_LOAD_AF(0, 0, afa) G8_LOAD_BF(0, 0, bf0)   // R(P1): tile0 h0

    const int nit = K / 128;
    for (int it = 0; it < nit - 1; ++it) {
        const int t = 2 * it;
        // P1: MFMA q0 (afa,bf0)@b0 | R:bf1<-b0.Bh1 | S:A(t+1,h1)->b1
        G8_LOAD_BF(0, 1, bf1)
        G8_STAGE(Ag, t + 1, 1, AsB, 1);
        G8_LGKMC(4);
        G8_MFMA(0, afa, bf0);
        G8_BARRIER();
        // P2: MFMA q1 (afa,bf1) | R:afb<-b0.Ah1 | S:B(t+1,h1)->b1
        G8_LOAD_AF(0, 1, afb)
        G8_STAGE(Bg, t + 1, 1, BsB, 1);
        G8_LGKMC(8);
        G8_MFMA(1, afa, bf1);
        G8_BARRIER();
        // P3: MFMA q2 (afb,bf0) | S:A(t+2,h0)->b0 | guard vmcnt(6)
        G8_STAGE(Ag, t + 2, 0, AsB, 0);
        G8_LGKMC(0);
        G8_MFMA(2, afb, bf0);
        G8_VMCNT(6);           // lands {A,B}(t+1,h0) for P4's reads
        G8_BARRIER();
        // P4: MFMA q3 (afb,bf1) | R:afa,bf0<-b1.h0 | S:B(t+2,h0)->b0 | g vmcnt(4)
        G8_LOAD_AF(1, 0, afa) G8_LOAD_BF(1, 0, bf0)
        G8_STAGE(Bg, t + 2, 0, BsB, 0);
        G8_MFMA(3, afb, bf1);
        G8_VMCNT(4);           // lands {A,B}(t+1,h1) for P5/P6 reads
        G8_BARRIER();
        // P5: MFMA q0 (afa,bf0)@b1 | R:bf1<-b1.Bh1 | S:A(t+2,h1)->b0
        G8_LOAD_BF(1, 1, bf1)
        G8_STAGE(Ag, t + 2, 1, AsB, 0);
        G8_LGKMC(4);
        G8_MFMA(0, afa, bf0);
        G8_BARRIER();
        // P6: MFMA q1 (afa,bf1) | R:afb<-b1.Ah1 | S:B(t+2,h1)->b0
        G8_LOAD_AF(1, 1, afb)
        G8_STAGE(Bg, t + 2, 1, BsB, 0);
        G8_LGKMC(8);
        G8_MFMA(1, afa, bf1);
        G8_BARRIER();
        // P7: MFMA q2 (afb,bf0) | S:A(t+3,h0)->b1 | guard vmcnt(6)
        G8_STAGE(Ag, t + 3, 0, AsB, 1);
        G8_LGKMC(0);
        G8_MFMA(2, afb, bf0);
        G8_VMCNT(6);           // lands {A,B}(t+2,h0) for P8's reads
        G8_BARRIER();
        // P8: MFMA q3 (afb,bf1) | R:afa,bf0<-b0.h0(t+2) | S:B(t+3,h0)->b1 | g4
        G8_LOAD_AF(0, 0, afa) G8_LOAD_BF(0, 0, bf0)
        G8_STAGE(Bg, t + 3, 0, BsB, 1);
        G8_MFMA(3, afb, bf1);
        G8_VMCNT(4);           // lands {A,B}(t+2,h1) for next-P1/P2 reads
        G8_BARRIER();
    }
    // ---- peel: tiles 2nit-2 (buf0), 2nit-1 (buf1); stage only t+1 h1 ----
    {
        const int t = 2 * (nit - 1);
        // P1
        G8_LOAD_BF(0, 1, bf1)
        G8_STAGE(Ag, t + 1, 1, AsB, 1);
        G8_LGKMC(4);
        G8_MFMA(0, afa, bf0);
        G8_BARRIER();
        // P2
        G8_LOAD_AF(0, 1, afb)
        G8_STAGE(Bg, t + 1, 1, BsB, 1);
        G8_LGKMC(8);
        G8_MFMA(1, afa, bf1);
        G8_BARRIER();
        // P3 (no stage); guard vmcnt(4): lands {A,B}(t+1,h0) [prev P7,P8]
        G8_LGKMC(0);
        G8_MFMA(2, afb, bf0);
        G8_VMCNT(4);
        G8_BARRIER();
        // P4: reads b1.h0; guard vmcnt(0): lands {A,B}(t+1,h1) [peel P1,P2]
        G8_LOAD_AF(1, 0, afa) G8_LOAD_BF(1, 0, bf0)
        G8_MFMA(3, afb, bf1);
        G8_VMCNT(0);
        G8_BARRIER();
        // P5
        G8_LOAD_BF(1, 1, bf1)
        G8_LGKMC(4);
        G8_MFMA(0, afa, bf0);
        G8_BARRIER();
        // P6
        G8_LOAD_AF(1, 1, afb)
        G8_LGKMC(8);
        G8_MFMA(1, afa, bf1);
        G8_BARRIER();
        // P7
        G8_LGKMC(0);
        G8_MFMA(2, afb, bf0);
        G8_BARRIER();
        // P8
        G8_MFMA(3, afb, bf1);
    }

    // ---- epilogue: D layout col = fr (n), row = quad*4 + r (m) ----
    #pragma unroll
    for (int q = 0; q < 4; ++q) {
        const int mh = q >> 1, nh = q & 1;
        #pragma unroll
        for (int j = 0; j < 2; ++j) {
            const int n = n0 + nh * 128 + brow + j * 16;
            const float bv = bias[n];
            #pragma unroll
            for (int i = 0; i < 4; ++i) {
                const int mb = m0 + mh * 128 + ww * 64 + i * 16 + quad * 4;
                #pragma unroll
                for (int r = 0; r < 4; ++r)
                    C[(size_t)(mb + r) * N + n] = acc[q][i][j][r] + bv;
            }
        }
    }
}

// ---------------- Pass 2 (fallback): 128x128 m97-structure GEMM -------------
__global__ __launch_bounds__(256, 2)
void gemm_bt_kernel(const unsigned short* __restrict__ Ab,
                    const unsigned short* __restrict__ Wb,
                    const float* __restrict__ bias, float* __restrict__ C,
                    int M, int N, int K)
{
    __shared__ __align__(16) unsigned short As[BM * BK];
    __shared__ __align__(16) unsigned short Bs[BN * BK];

    const int tid = threadIdx.x;
    const int m0  = blockIdx.x * BM;
    const int n0  = blockIdx.y * BN;

    const int lane = tid & 63;
    const int wave = tid >> 6;
    const int wm   = (wave >> 1) * 64;
    const int wn   = (wave & 1) * 64;
    const int fr   = lane & 15;
    const int quad = lane >> 4;
    const int sw   = fr & 7;

    f32x4 acc[4][4];
    #pragma unroll
    for (int i = 0; i < 4; ++i)
        #pragma unroll
        for (int j = 0; j < 4; ++j)
            acc[i][j] = (f32x4){0.f, 0.f, 0.f, 0.f};

    const int ktiles = K / BK;
    for (int kt = 0; kt < ktiles; ++kt) {
        const int k0 = kt * BK;
        #pragma unroll
        for (int i = 0; i < 4; ++i) {
            const int c    = i * 256 + tid;
            const int row  = c >> 3;
            const int g    = (c & 7) ^ (row & 7);
            const int cole = g * 8;
            gl_lds16(Ab + (size_t)(m0 + row) * K + k0 + cole, (char*)As + c * 16);
            gl_lds16(Wb + (size_t)(n0 + row) * K + k0 + cole, (char*)Bs + c * 16);
        }
        __syncthreads();

        #pragma unroll
        for (int ks = 0; ks < 2; ++ks) {
            bf16x8 af[4], bfg[4];
            #pragma unroll
            for (int i = 0; i < 4; ++i) {
                const int row = wm + i * 16 + fr;
                const int p   = (ks * 4 + quad) ^ sw;
                af[i] = *(const bf16x8*)&As[row * BK + p * 8];
            }
            #pragma unroll
            for (int j = 0; j < 4; ++j) {
                const int row = wn + j * 16 + fr;
                const int p   = (ks * 4 + quad) ^ sw;
                bfg[j] = *(const bf16x8*)&Bs[row * BK + p * 8];
            }
            #pragma unroll
            for (int i = 0; i < 4; ++i)
                #pragma unroll
                for (int j = 0; j < 4; ++j)
                    acc[i][j] = __builtin_amdgcn_mfma_f32_16x16x32_bf16(af[i], bfg[j], acc[i][j], 0, 0, 0);
        }
        __syncthreads();
    }

    #pragma unroll
    for (int j = 0; j < 4; ++j) {
        const int n = n0 + wn + j * 16 + fr;
        const float bv = bias[n];
        #pragma unroll
        for (int i = 0; i < 4; ++i) {
            const int mb = m0 + wm + i * 16 + quad * 4;
            #pragma unroll
            for (int r = 0; r < 4; ++r)
                C[(size_t)(mb + r) * N + n] = acc[i][j][r] + bv;
        }
    }
}

// ---------------- Fallback: round-1 fused kernel ----------------
__global__ __launch_bounds__(256, 2)
void q4gemm_fused(const float* __restrict__ A, const int* __restrict__ Q,
                  const float* __restrict__ S, const int* __restrict__ Zp,
                  const float* __restrict__ bias, float* __restrict__ C,
                  int M, int N, int K, int nb)
{
    __shared__ __align__(16) unsigned short As[BM * LDSN];
    __shared__ __align__(16) unsigned short Bs[BN * LDSN];

    const int tid = threadIdx.x;
    const int m0  = blockIdx.x * BM;
    const int n0  = blockIdx.y * BN;
    const int srow = tid >> 4;
    const int scol = (tid & 15) << 2;
    const int lane = tid & 63;
    const int wave = tid >> 6;
    const int wm   = (wave >> 1) * 64;
    const int wn   = (wave & 1) * 64;
    const int fr   = lane & 15;
    const int quad = lane >> 4;

    f32x4 acc[4][4];
    #pragma unroll
    for (int i = 0; i < 4; ++i)
        #pragma unroll
        for (int j = 0; j < 4; ++j)
            acc[i][j] = (f32x4){0.f, 0.f, 0.f, 0.f};

    const int ktiles = K / BK;
    for (int kt = 0; kt < ktiles; ++kt) {
        const int k0 = kt * BK;
        #pragma unroll
        for (int i = 0; i < 8; ++i) {
            const int r = i * 16 + srow;
            const float4 v = *(const float4*)(A + (size_t)(m0 + r) * K + k0 + scol);
            uint2 p; p.x = pack2(v.x, v.y); p.y = pack2(v.z, v.w);
            *(uint2*)&As[r * LDSN + scol] = p;
        }
        #pragma unroll
        for (int i = 0; i < 8; ++i) {
            const int r = i * 16 + srow;
            const int n = n0 + r;
            const int4 q = *(const int4*)(Q + (size_t)n * K + k0 + scol);
            const float s  = S[(size_t)n * nb + kt];
            const float zs = (float)Zp[(size_t)n * nb + kt] * s;
            uint2 p;
            p.x = pack2((float)q.x * s - zs, (float)q.y * s - zs);
            p.y = pack2((float)q.z * s - zs, (float)q.w * s - zs);
            *(uint2*)&Bs[r * LDSN + scol] = p;
        }
        __syncthreads();
        #pragma unroll
        for (int ks = 0; ks < 2; ++ks) {
            bf16x8 af[4], bfg[4];
            #pragma unroll
            for (int i = 0; i < 4; ++i)
                af[i] = *(const bf16x8*)&As[(wm + i * 16 + fr) * LDSN + ks * 32 + quad * 8];
            #pragma unroll
            for (int j = 0; j < 4; ++j)
                bfg[j] = *(const bf16x8*)&Bs[(wn + j * 16 + fr) * LDSN + ks * 32 + quad * 8];
            #pragma unroll
            for (int i = 0; i < 4; ++i)
                #pragma unroll
                for (int j = 0; j < 4; ++j)
                    acc[i][j] = __builtin_amdgcn_mfma_f32_16x16x32_bf16(af[i], bfg[j], acc[i][j], 0, 0, 0);
        }
        __syncthreads();
    }
    #pragma unroll
    for (int j = 0; j < 4; ++j) {
        const int n = n0 + wn + j * 16 + fr;
        const float bv = bias[n];
        #pragma unroll
        for (int i = 0; i < 4; ++i) {
            const int mb = m0 + wm + i * 16 + quad * 4;
            #pragma unroll
            for (int r = 0; r < 4; ++r)
                C[(size_t)(mb + r) * N + n] = acc[i][j][r] + bv;
        }
    }
}

extern "C" void kernel_launch(void* const* d_in, const int* in_sizes, int n_in,
                              void* d_out, int out_size, void* d_ws, size_t ws_size,
                              hipStream_t stream) {
    const float* A    = (const float*)d_in[0];
    const int*   Q    = (const int*)d_in[1];
    const float* S    = (const float*)d_in[2];
    const int*   Zp   = (const int*)d_in[3];
    const float* bias = (const float*)d_in[4];
    float* C = (float*)d_out;

    const int N  = in_sizes[4];
    const int K  = in_sizes[1] / N;
    const int M  = in_sizes[0] / K;
    const int nb = in_sizes[2] / N;

    const size_t needA = (size_t)M * K * 2;
    const size_t needW = (size_t)N * K * 2;

    if (ws_size >= needA + needW && (K % 2048) == 0) {
        unsigned short* Ab = (unsigned short*)d_ws;
        unsigned short* Wb = (unsigned short*)((char*)d_ws + needA);

        dim3 pgrid(K / 2048, M + N);
        prep_kernel<<<pgrid, 256, 0, stream>>>(A, Q, S, Zp, Ab, Wb, M, K, nb);

        if ((M % 256) == 0 && (N % 256) == 0 && (K % 256) == 0) {
            gemm8_kernel<<<dim3((M / 256) * (N / 256)), dim3(512), 0, stream>>>(
                Ab, Wb, bias, C, M, N, K);
        } else {
            dim3 grid(M / BM, N / BN);
            gemm_bt_kernel<<<grid, dim3(256), 0, stream>>>(Ab, Wb, bias, C, M, N, K);
        }
    } else {
        dim3 grid(M / BM, N / BN);
        q4gemm_fused<<<grid, dim3(256), 0, stream>>>(A, Q, S, Zp, bias, C, M, N, K, nb);
    }
}

// Round 6
// 677.657 us; speedup vs baseline: 1.4158x; 1.4158x over previous
//
#include <hip/hip_runtime.h>

// BlkQ4Linear: out[m,n] = sum_k in[m,k]*(q[n,k]-zp[n,k/64])*s[n,k/64] + bias[n]
// M=4096 K=4096 N=11008.
// Round 9: R8's pipelined GEMM spilled (WRITE_SIZE 189->332 MB = scratch in
// the K-loop; scratch ops also poison counted-vmcnt guards) -> revert GEMM to
// the VERIFIED R7 version (362 us, MfmaUtil 45.8, zero conflicts, clean
// write traffic). This round attacks the ~290 us non-GEMM residue instead:
// prep_kernel moves from a 30208-block launch (grid 2 x 15104) to a
// grid-stride form (2 x 2048, rows strided by gridDim.y). Same math, same
// coalescing, 7.4x fewer blocks/waves.

#define BM 128
#define BN 128
#define BK 64
#define LDSN 72  // fused-fallback LDS pad

typedef __attribute__((ext_vector_type(8))) short bf16x8;
typedef __attribute__((ext_vector_type(4))) float f32x4;

__device__ __forceinline__ unsigned short f2bf(float f) {
    union { float f; unsigned int u; } v; v.f = f;
    unsigned int u = v.u;
    u += 0x7FFFu + ((u >> 16) & 1u);   // RNE
    return (unsigned short)(u >> 16);
}
__device__ __forceinline__ unsigned int pack2(float a, float b) {
    return (unsigned int)f2bf(a) | ((unsigned int)f2bf(b) << 16);
}

__device__ __forceinline__ void gl_lds16(const void* gp, void* lp) {
    __builtin_amdgcn_global_load_lds(
        (const __attribute__((address_space(1))) unsigned int*)gp,
        (__attribute__((address_space(3))) unsigned int*)lp,
        16, 0, 0);
}

__device__ __forceinline__ unsigned lds_off(const void* p) {
    return (unsigned)(unsigned long long)
        (const __attribute__((address_space(3))) void*)p;
}

template<int IMM>
__device__ __forceinline__ bf16x8 ds128(unsigned a) {
    bf16x8 d;
    asm volatile("ds_read_b128 %0, %1 offset:%2"
                 : "=v"(d) : "v"(a), "i"(IMM));
    return d;
}

// ---------------- Pass 1 (merged, grid-stride): A->bf16, Q->bf16 W ----------
// rows [0,M) convert A; rows [M,M+N) dequant W. Row loop strided by
// gridDim.y (launched at 2048); k covered by blockIdx.x * 256 threads * 8.
__global__ __launch_bounds__(256)
void prep_kernel(const float* __restrict__ A, const int* __restrict__ Q,
                 const float* __restrict__ S, const int* __restrict__ Zp,
                 unsigned short* __restrict__ Ab, unsigned short* __restrict__ W,
                 int M, int K, int nb, int MN)
{
    const int k = (blockIdx.x * 256 + threadIdx.x) * 8;
    if (k >= K) return;
    const int kb = k >> 6;
    for (int y = blockIdx.y; y < MN; y += gridDim.y) {
        if (y < M) {
            const float4* ap = (const float4*)(A + (size_t)y * K + k);
            float4 a0 = ap[0], a1 = ap[1];
            uint4 o;
            o.x = pack2(a0.x, a0.y); o.y = pack2(a0.z, a0.w);
            o.z = pack2(a1.x, a1.y); o.w = pack2(a1.z, a1.w);
            *(uint4*)(Ab + (size_t)y * K + k) = o;
        } else {
            const int n = y - M;
            const float s  = S[(size_t)n * nb + kb];
            const float zs = (float)Zp[(size_t)n * nb + kb] * s;
            const int4* qp = (const int4*)(Q + (size_t)n * K + k);
            int4 q0 = qp[0], q1 = qp[1];
            uint4 o;
            o.x = pack2((float)q0.x * s - zs, (float)q0.y * s - zs);
            o.y = pack2((float)q0.z * s - zs, (float)q0.w * s - zs);
            o.z = pack2((float)q1.x * s - zs, (float)q1.y * s - zs);
            o.w = pack2((float)q1.z * s - zs, (float)q1.w * s - zs);
            *(uint4*)(W + (size_t)n * K + k) = o;
        }
    }
}

// ---------------- Pass 2: 256x256 8-phase bf16 GEMM (VERIFIED R7) -----------
// Waves 2(M) x 4(N); per-wave 128x64 C. Per phase one 128x128 C-quadrant,
// 16 MFMA/wave. LDS As[2][256][64], Bs[2][256][64] (128 KiB), tile t->buf t&1.
// Swizzle: physical 16B chunk p of row r holds logical chunk p^(r&7); applied
// on the global source column at staging (LDS dst linear, HW reqt), inverted
// in the read address. Measured 0 bank-conflict cycles.
// Read pattern per K-tile: P1: 8 A + 4 B(nh0) | P2: 4 B(nh1) |
// P3: 8 A (bf0 resident) | P4: 0 (af, bf1 resident). 24 reads.

#define G8_BARRIER() asm volatile("s_barrier" ::: "memory")
#define G8_VMCNT(n)  asm volatile("s_waitcnt vmcnt(" #n ")" ::: "memory")
#define G8_LGKMC(n)  asm volatile("s_waitcnt lgkmcnt(" #n ")" ::: "memory")
#define G8_LGKM0()   do { asm volatile("s_waitcnt lgkmcnt(0)" ::: "memory"); \
    __builtin_amdgcn_sched_barrier(0); } while (0)

#define G8_STAGE(G, kt, h, base, b)                                          \
  do {                                                                       \
    const unsigned short* _s = (G) + (long)(kt) * 64 + (long)(h) * 128 * K;  \
    gl_lds16(_s + aoff0, (base) + (b) * 32768 + (h) * 16384 + lds0);         \
    gl_lds16(_s + aoff1, (base) + (b) * 32768 + (h) * 16384 + lds1);         \
  } while (0)

#define G8_LOAD_AF(b, mh)                                                    \
  af[0][0] = ds128<(b)*32768 + (mh)*16384 + 0*2048>(pA0);                    \
  af[1][0] = ds128<(b)*32768 + (mh)*16384 + 1*2048>(pA0);                    \
  af[2][0] = ds128<(b)*32768 + (mh)*16384 + 2*2048>(pA0);                    \
  af[3][0] = ds128<(b)*32768 + (mh)*16384 + 3*2048>(pA0);                    \
  af[0][1] = ds128<(b)*32768 + (mh)*16384 + 0*2048>(pA1);                    \
  af[1][1] = ds128<(b)*32768 + (mh)*16384 + 1*2048>(pA1);                    \
  af[2][1] = ds128<(b)*32768 + (mh)*16384 + 2*2048>(pA1);                    \
  af[3][1] = ds128<(b)*32768 + (mh)*16384 + 3*2048>(pA1);

#define G8_LOAD_BF(b, nh, BF)                                                \
  BF[0][0] = ds128<(b)*32768 + (nh)*16384 + 0*2048>(pB0);                    \
  BF[1][0] = ds128<(b)*32768 + (nh)*16384 + 1*2048>(pB0);                    \
  BF[0][1] = ds128<(b)*32768 + (nh)*16384 + 0*2048>(pB1);                    \
  BF[1][1] = ds128<(b)*32768 + (nh)*16384 + 1*2048>(pB1);

#define G8_MFMA(q, BF)                                                       \
  __builtin_amdgcn_s_setprio(1);                                             \
  { _Pragma("unroll") for (int _i = 0; _i < 4; ++_i)                         \
    _Pragma("unroll") for (int _j = 0; _j < 2; ++_j) {                       \
      acc[q][_i][_j] = __builtin_amdgcn_mfma_f32_16x16x32_bf16(              \
          af[_i][0], BF[_j][0], acc[q][_i][_j], 0, 0, 0);                    \
      acc[q][_i][_j] = __builtin_amdgcn_mfma_f32_16x16x32_bf16(              \
          af[_i][1], BF[_j][1], acc[q][_i][_j], 0, 0, 0);                    \
  } }                                                                        \
  __builtin_amdgcn_s_setprio(0);

__global__ __launch_bounds__(512, 2)
void gemm8_kernel(const unsigned short* __restrict__ Ab,
                  const unsigned short* __restrict__ Wb,
                  const float* __restrict__ bias, float* __restrict__ C,
                  int M, int N, int K)
{
    __shared__ __align__(16) unsigned short As[2][256][64];
    __shared__ __align__(16) unsigned short Bs[2][256][64];

    const int tid  = threadIdx.x;

    // Bijective XCD-chunked swizzle (T1/m204), M-fastest decode.
    const int nwg = gridDim.x;
    int wg = blockIdx.x;
    {
        const int q8 = nwg >> 3, r8 = nwg & 7, x = wg & 7, s = wg >> 3;
        wg = (x < r8 ? x * (q8 + 1) : r8 * (q8 + 1) + (x - r8) * q8) + s;
    }
    const int gx = M / 256;
    const int m0 = (wg % gx) * 256;
    const int n0 = (wg / gx) * 256;

    const int lane = tid & 63;
    const int wave = tid >> 6;
    const int ww   = wave >> 2;       // 0..1, m-dir
    const int wv   = wave & 3;        // 0..3, n-dir
    const int fr   = lane & 15;
    const int quad = lane >> 4;
    const int sw   = fr & 7;

    // staging constants: thread covers chunks tid and 512+tid of each half
    const int rl0 = tid >> 3;
    const int rl1 = (512 + tid) >> 3;
    const int pp  = tid & 7;
    const long aoff0 = (long)rl0 * K + (long)((pp ^ (rl0 & 7)) * 8);
    const long aoff1 = (long)rl1 * K + (long)((pp ^ (rl1 & 7)) * 8);
    const int lds0 = tid * 16;
    const int lds1 = (512 + tid) * 16;

    // fragment-read bases: logical chunk l=ks*4+quad at physical (l^sw)*16
    const int ck0 = ((quad    ) ^ sw) * 16;
    const int ck1 = ((quad + 4) ^ sw) * 16;
    const int arow = ww * 64 + fr;
    const int brow = wv * 32 + fr;

    char* AsB = (char*)&As[0][0][0];
    char* BsB = (char*)&Bs[0][0][0];
    const unsigned pA0 = lds_off(AsB) + arow * 128 + ck0;
    const unsigned pA1 = lds_off(AsB) + arow * 128 + ck1;
    const unsigned pB0 = lds_off(BsB) + brow * 128 + ck0;
    const unsigned pB1 = lds_off(BsB) + brow * 128 + ck1;

    const unsigned short* Ag = Ab + (size_t)m0 * K;
    const unsigned short* Bg = Wb + (size_t)n0 * K;

    f32x4 acc[4][4][2];
    #pragma unroll
    for (int q = 0; q < 4; ++q)
        #pragma unroll
        for (int i = 0; i < 4; ++i)
            #pragma unroll
            for (int j = 0; j < 2; ++j)
                acc[q][i][j] = (f32x4){0.f, 0.f, 0.f, 0.f};

    bf16x8 af[4][2], bf0[2][2], bf1[2][2];

    // ---- prologue: tile0 (buf0) fully + A0,B0 of tile1 (buf1) ----
    G8_STAGE(Ag, 0, 0, AsB, 0);
    G8_STAGE(Bg, 0, 0, BsB, 0);
    G8_STAGE(Ag, 0, 1, AsB, 0);
    G8_STAGE(Bg, 0, 1, BsB, 0);
    G8_STAGE(Ag, 1, 0, AsB, 1);
    G8_STAGE(Bg, 1, 0, BsB, 1);
    G8_VMCNT(4);              // tile0's 8 loads landed; A0,B0(1) in flight
    G8_BARRIER();

    const int nit = K / 128;
    for (int it = 0; it < nit - 1; ++it) {
        const int t = 2 * it;
        // P1: q(0,0) buf0 | 12 reads | stage A1(t+1)->buf1 | vmcnt(6)
        G8_LOAD_AF(0, 0) G8_LOAD_BF(0, 0, bf0)
        G8_STAGE(Ag, t + 1, 1, AsB, 1);
        G8_LGKMC(8);
        G8_BARRIER(); G8_LGKM0();
        G8_MFMA(0, bf0);
        G8_VMCNT(6);           // lands A1,B1(t) for P2/P3
        G8_BARRIER();
        // P2: q(0,1) buf0 | 4 reads | stage B1(t+1)->buf1
        G8_LOAD_BF(0, 1, bf1)
        G8_STAGE(Bg, t + 1, 1, BsB, 1);
        G8_BARRIER(); G8_LGKM0();
        G8_MFMA(1, bf1);
        G8_BARRIER();
        // P3: q(1,0) buf0 | 8 reads (bf0 resident) | stage A0(t+2)->buf0
        G8_LOAD_AF(0, 1)
        G8_STAGE(Ag, t + 2, 0, AsB, 0);
        G8_BARRIER(); G8_LGKM0();
        G8_MFMA(2, bf0);
        G8_BARRIER();
        // P4: q(1,1) buf0 | 0 reads (af, bf1 resident) | stage B0(t+2)->buf0
        G8_STAGE(Bg, t + 2, 0, BsB, 0);
        G8_BARRIER();
        G8_MFMA(3, bf1);
        G8_VMCNT(8);           // lands A0,B0(t+1) for P5
        G8_BARRIER();
        // P5: q(0,0) buf1 | 12 reads | stage A1(t+2)->buf0 | vmcnt(6)
        G8_LOAD_AF(1, 0) G8_LOAD_BF(1, 0, bf0)
        G8_STAGE(Ag, t + 2, 1, AsB, 0);
        G8_LGKMC(8);
        G8_BARRIER(); G8_LGKM0();
        G8_MFMA(0, bf0);
        G8_VMCNT(6);           // lands A1,B1(t+1) for P6/P7
        G8_BARRIER();
        // P6: q(0,1) buf1 | 4 reads | stage B1(t+2)->buf0
        G8_LOAD_BF(1, 1, bf1)
        G8_STAGE(Bg, t + 2, 1, BsB, 0);
        G8_BARRIER(); G8_LGKM0();
        G8_MFMA(1, bf1);
        G8_BARRIER();
        // P7: q(1,0) buf1 | 8 reads | stage A0(t+3)->buf1
        G8_LOAD_AF(1, 1)
        G8_STAGE(Ag, t + 3, 0, AsB, 1);
        G8_BARRIER(); G8_LGKM0();
        G8_MFMA(2, bf0);
        G8_BARRIER();
        // P8: q(1,1) buf1 | 0 reads | stage B0(t+3)->buf1 | vmcnt(8)
        G8_STAGE(Bg, t + 3, 0, BsB, 1);
        G8_BARRIER();
        G8_MFMA(3, bf1);
        G8_VMCNT(8);           // lands A0,B0(t+2) for next P1
        G8_BARRIER();
    }
    // ---- peeled last iteration (tiles 2*nit-2, 2*nit-1): drain ----
    {
        G8_LOAD_AF(0, 0) G8_LOAD_BF(0, 0, bf0)
        G8_STAGE(Ag, 2 * nit - 1, 1, AsB, 1);
        G8_LGKMC(8);
        G8_BARRIER(); G8_LGKM0(); G8_MFMA(0, bf0); G8_VMCNT(6); G8_BARRIER();

        G8_LOAD_BF(0, 1, bf1)
        G8_STAGE(Bg, 2 * nit - 1, 1, BsB, 1);
        G8_BARRIER(); G8_LGKM0(); G8_MFMA(1, bf1); G8_BARRIER();

        G8_LOAD_AF(0, 1)
        G8_BARRIER(); G8_LGKM0(); G8_MFMA(2, bf0); G8_BARRIER();

        G8_BARRIER(); G8_MFMA(3, bf1); G8_VMCNT(4); G8_BARRIER();

        G8_LOAD_AF(1, 0) G8_LOAD_BF(1, 0, bf0)
        G8_BARRIER(); G8_LGKM0(); G8_MFMA(0, bf0); G8_VMCNT(0); G8_BARRIER();

        G8_LOAD_BF(1, 1, bf1)
        G8_BARRIER(); G8_LGKM0(); G8_MFMA(1, bf1); G8_BARRIER();

        G8_LOAD_AF(1, 1)
        G8_BARRIER(); G8_LGKM0(); G8_MFMA(2, bf0); G8_BARRIER();

        G8_MFMA(3, bf1);
    }

    // ---- epilogue: D layout col = fr (n), row = quad*4 + r (m) ----
    #pragma unroll
    for (int q = 0; q < 4; ++q) {
        const int mh = q >> 1, nh = q & 1;
        #pragma unroll
        for (int j = 0; j < 2; ++j) {
            const int n = n0 + nh * 128 + brow + j * 16;
            const float bv = bias[n];
            #pragma unroll
            for (int i = 0; i < 4; ++i) {
                const int mb = m0 + mh * 128 + ww * 64 + i * 16 + quad * 4;
                #pragma unroll
                for (int r = 0; r < 4; ++r)
                    C[(size_t)(mb + r) * N + n] = acc[q][i][j][r] + bv;
            }
        }
    }
}

// ---------------- Pass 2 (fallback): 128x128 m97-structure GEMM -------------
__global__ __launch_bounds__(256, 2)
void gemm_bt_kernel(const unsigned short* __restrict__ Ab,
                    const unsigned short* __restrict__ Wb,
                    const float* __restrict__ bias, float* __restrict__ C,
                    int M, int N, int K)
{
    __shared__ __align__(16) unsigned short As[BM * BK];
    __shared__ __align__(16) unsigned short Bs[BN * BK];

    const int tid = threadIdx.x;
    const int m0  = blockIdx.x * BM;
    const int n0  = blockIdx.y * BN;

    const int lane = tid & 63;
    const int wave = tid >> 6;
    const int wm   = (wave >> 1) * 64;
    const int wn   = (wave & 1) * 64;
    const int fr   = lane & 15;
    const int quad = lane >> 4;
    const int sw   = fr & 7;

    f32x4 acc[4][4];
    #pragma unroll
    for (int i = 0; i < 4; ++i)
        #pragma unroll
        for (int j = 0; j < 4; ++j)
            acc[i][j] = (f32x4){0.f, 0.f, 0.f, 0.f};

    const int ktiles = K / BK;
    for (int kt = 0; kt < ktiles; ++kt) {
        const int k0 = kt * BK;
        #pragma unroll
        for (int i = 0; i < 4; ++i) {
            const int c    = i * 256 + tid;
            const int row  = c >> 3;
            const int g    = (c & 7) ^ (row & 7);
            const int cole = g * 8;
            gl_lds16(Ab + (size_t)(m0 + row) * K + k0 + cole, (char*)As + c * 16);
            gl_lds16(Wb + (size_t)(n0 + row) * K + k0 + cole, (char*)Bs + c * 16);
        }
        __syncthreads();

        #pragma unroll
        for (int ks = 0; ks < 2; ++ks) {
            bf16x8 af[4], bfg[4];
            #pragma unroll
            for (int i = 0; i < 4; ++i) {
                const int row = wm + i * 16 + fr;
                const int p   = (ks * 4 + quad) ^ sw;
                af[i] = *(const bf16x8*)&As[row * BK + p * 8];
            }
            #pragma unroll
            for (int j = 0; j < 4; ++j) {
                const int row = wn + j * 16 + fr;
                const int p   = (ks * 4 + quad) ^ sw;
                bfg[j] = *(const bf16x8*)&Bs[row * BK + p * 8];
            }
            #pragma unroll
            for (int i = 0; i < 4; ++i)
                #pragma unroll
                for (int j = 0; j < 4; ++j)
                    acc[i][j] = __builtin_amdgcn_mfma_f32_16x16x32_bf16(af[i], bfg[j], acc[i][j], 0, 0, 0);
        }
        __syncthreads();
    }

    #pragma unroll
    for (int j = 0; j < 4; ++j) {
        const int n = n0 + wn + j * 16 + fr;
        const float bv = bias[n];
        #pragma unroll
        for (int i = 0; i < 4; ++i) {
            const int mb = m0 + wm + i * 16 + quad * 4;
            #pragma unroll
            for (int r = 0; r < 4; ++r)
                C[(size_t)(mb + r) * N + n] = acc[i][j][r] + bv;
        }
    }
}

// ---------------- Fallback: round-1 fused kernel ----------------
__global__ __launch_bounds__(256, 2)
void q4gemm_fused(const float* __restrict__ A, const int* __restrict__ Q,
                  const float* __restrict__ S, const int* __restrict__ Zp,
                  const float* __restrict__ bias, float* __restrict__ C,
                  int M, int N, int K, int nb)
{
    __shared__ __align__(16) unsigned short As[BM * LDSN];
    __shared__ __align__(16) unsigned short Bs[BN * LDSN];

    const int tid = threadIdx.x;
    const int m0  = blockIdx.x * BM;
    const int n0  = blockIdx.y * BN;
    const int srow = tid >> 4;
    const int scol = (tid & 15) << 2;
    const int lane = tid & 63;
    const int wave = tid >> 6;
    const int wm   = (wave >> 1) * 64;
    const int wn   = (wave & 1) * 64;
    const int fr   = lane & 15;
    const int quad = lane >> 4;

    f32x4 acc[4][4];
    #pragma unroll
    for (int i = 0; i < 4; ++i)
        #pragma unroll
        for (int j = 0; j < 4; ++j)
            acc[i][j] = (f32x4){0.f, 0.f, 0.f, 0.f};

    const int ktiles = K / BK;
    for (int kt = 0; kt < ktiles; ++kt) {
        const int k0 = kt * BK;
        #pragma unroll
        for (int i = 0; i < 8; ++i) {
            const int r = i * 16 + srow;
            const float4 v = *(const float4*)(A + (size_t)(m0 + r) * K + k0 + scol);
            uint2 p; p.x = pack2(v.x, v.y); p.y = pack2(v.z, v.w);
            *(uint2*)&As[r * LDSN + scol] = p;
        }
        #pragma unroll
        for (int i = 0; i < 8; ++i) {
            const int r = i * 16 + srow;
            const int n = n0 + r;
            const int4 q = *(const int4*)(Q + (size_t)n * K + k0 + scol);
            const float s  = S[(size_t)n * nb + kt];
            const float zs = (float)Zp[(size_t)n * nb + kt] * s;
            uint2 p;
            p.x = pack2((float)q.x * s - zs, (float)q.y * s - zs);
            p.y = pack2((float)q.z * s - zs, (float)q.w * s - zs);
            *(uint2*)&Bs[r * LDSN + scol] = p;
        }
        __syncthreads();
        #pragma unroll
        for (int ks = 0; ks < 2; ++ks) {
            bf16x8 af[4], bfg[4];
            #pragma unroll
            for (int i = 0; i < 4; ++i)
                af[i] = *(const bf16x8*)&As[(wm + i * 16 + fr) * LDSN + ks * 32 + quad * 8];
            #pragma unroll
            for (int j = 0; j < 4; ++j)
                bfg[j] = *(const bf16x8*)&Bs[(wn + j * 16 + fr) * LDSN + ks * 32 + quad * 8];
            #pragma unroll
            for (int i = 0; i < 4; ++i)
                #pragma unroll
                for (int j = 0; j < 4; ++j)
                    acc[i][j] = __builtin_amdgcn_mfma_f32_16x16x32_bf16(af[i], bfg[j], acc[i][j], 0, 0, 0);
        }
        __syncthreads();
    }
    #pragma unroll
    for (int j = 0; j < 4; ++j) {
        const int n = n0 + wn + j * 16 + fr;
        const float bv = bias[n];
        #pragma unroll
        for (int i = 0; i < 4; ++i) {
            const int mb = m0 + wm + i * 16 + quad * 4;
            #pragma unroll
            for (int r = 0; r < 4; ++r)
                C[(size_t)(mb + r) * N + n] = acc[i][j][r] + bv;
        }
    }
}

extern "C" void kernel_launch(void* const* d_in, const int* in_sizes, int n_in,
                              void* d_out, int out_size, void* d_ws, size_t ws_size,
                              hipStream_t stream) {
    const float* A    = (const float*)d_in[0];
    const int*   Q    = (const int*)d_in[1];
    const float* S    = (const float*)d_in[2];
    const int*   Zp   = (const int*)d_in[3];
    const float* bias = (const float*)d_in[4];
    float* C = (float*)d_out;

    const int N  = in_sizes[4];
    const int K  = in_sizes[1] / N;
    const int M  = in_sizes[0] / K;
    const int nb = in_sizes[2] / N;

    const size_t needA = (size_t)M * K * 2;
    const size_t needW = (size_t)N * K * 2;

    if (ws_size >= needA + needW && (K % 2048) == 0) {
        unsigned short* Ab = (unsigned short*)d_ws;
        unsigned short* Wb = (unsigned short*)((char*)d_ws + needA);

        const int MN = M + N;
        const int gy = MN < 2048 ? MN : 2048;
        dim3 pgrid(K / 2048, gy);
        prep_kernel<<<pgrid, 256, 0, stream>>>(A, Q, S, Zp, Ab, Wb, M, K, nb, MN);

        if ((M % 256) == 0 && (N % 256) == 0 && (K % 256) == 0) {
            gemm8_kernel<<<dim3((M / 256) * (N / 256)), dim3(512), 0, stream>>>(
                Ab, Wb, bias, C, M, N, K);
        } else {
            dim3 grid(M / BM, N / BN);
            gemm_bt_kernel<<<grid, dim3(256), 0, stream>>>(Ab, Wb, bias, C, M, N, K);
        }
    } else {
        dim3 grid(M / BM, N / BN);
        q4gemm_fused<<<grid, dim3(256), 0, stream>>>(A, Q, S, Zp, bias, C, M, N, K, nb);
    }
}